// Round 20
// baseline (56.036 us; speedup 1.0000x reference)
//
#include <hip/hip_runtime.h>
#include <hip/hip_fp16.h>
#include <math.h>
#include <stdint.h>

#define U 50
#define TT 100
#define BB 256

typedef _Float16 f16x8 __attribute__((ext_vector_type(8)));
typedef float    f32x4 __attribute__((ext_vector_type(4)));

__device__ __forceinline__ float sigmoid_fast(float x) {
    return 1.0f / (1.0f + __expf(-x));   // saturates cleanly, no NaN
}
__device__ __forceinline__ float tanh_fast(float x) {
    float e = __expf(2.0f * x);
    return 1.0f - 2.0f / (e + 1.0f);     // saturates cleanly, no NaN
}
__device__ __forceinline__ float param_act(float x, float mn, float mx) {
    float scale = 0.5f * (mx - mn);
    return tanh_fast(x) * scale + mn + scale;
}

// lgkm-only barrier: no vmcnt drain in the loop (round-14 lesson).
#define BAR() do {                                            \
    asm volatile("s_waitcnt lgkmcnt(0)" ::: "memory");        \
    __builtin_amdgcn_s_barrier();                             \
    asm volatile("" ::: "memory");                            \
} while (0)

// 4 waves per batch; wave w owns UNITS 16w..16w+15 and computes ALL 4 gates
// for them: 8 MFMA (tiles (g, nt=w), B-frag col c = unit 16w+c). The MFMA
// sums over k across lanes, so every lane (c,q) holds the complete z of all
// 4 gates for its unit in-lane -> NO cross-wave gate exchange (round 18's
// zex round-trip eliminated). c/h chain is lane-local (q-redundant x4);
// q==0 lanes write h(t+1)/x(t+1) into the double-buffered h~, giving ONE
// lgkm-only barrier per step. K=64 = [h(50)|x(4)|1|0..]: x + bias folded
// into the matmul. B-fragments live in AGPR, read free by the matrix pipe.
__global__ __launch_bounds__(256, 1) void encoder_kernel(
    const float* __restrict__ x,        // (B,T,4)
    const float* __restrict__ state,    // (B,T,4)
    const float* __restrict__ kernel,   // (4,200)
    const float* __restrict__ rec,      // (50,200)
    const float* __restrict__ bias,     // (200,)
    const float* __restrict__ w_dv, const float* __restrict__ b_dv,
    const float* __restrict__ w_dt, const float* __restrict__ b_dt,
    const float* __restrict__ w_mj, const float* __restrict__ b_mj,
    const float* __restrict__ w_ma, const float* __restrict__ b_ma,
    const float* __restrict__ w_mi, const float* __restrict__ b_mi,
    float* __restrict__ out)            // act_seq (B*T) then idm (B*5)
{
    const int b    = blockIdx.x;
    const int tid  = threadIdx.x;
    const int w    = tid >> 6;          // unit group 16w..16w+15
    const int l    = tid & 63;
    const int c    = l & 15;
    const int q    = l >> 4;
    const int unit = 16 * w + c;        // this lane's unit (4 q-copies)

    __shared__ __align__(16) float4 xlds[TT];        // staged x(b,:,:)
    __shared__ __align__(16) _Float16 hbb[2][64];    // dbuf h~ = [h|x|1|0]
    __shared__ float idm[8];

    // ---- B-fragments: wf[g][ks] elem e = W~_g[k=32*ks+8q+e][unit] ----
    f16x8 wf[4][2];
    #pragma unroll
    for (int g = 0; g < 4; ++g) {
        #pragma unroll
        for (int ks = 0; ks < 2; ++ks) {
            f16x8 f;
            #pragma unroll
            for (int e = 0; e < 8; ++e) {
                const int j = 32 * ks + 8 * q + e;
                float v = 0.0f;
                if (unit < U) {
                    if (j < U)           v = rec[j * 200 + g * U + unit];
                    else if (j < U + 4)  v = kernel[(j - U) * 200 + g * U + unit];
                    else if (j == U + 4) v = bias[g * U + unit];
                }
                f[e] = (_Float16)v;
            }
            wf[g][ks] = f;
        }
    }

    // ---- stage x; init h~ buffers: buf0 = [0|x(0)|1|0], buf1 = [..|1|0] ----
    if (tid < TT) xlds[tid] = ((const float4*)(x + (size_t)b * TT * 4))[tid];
    if (tid < 64) {
        _Float16 v0 = (_Float16)0.0f, v1 = (_Float16)0.0f;
        if (tid >= U && tid < U + 4) v0 = (_Float16)x[(size_t)b * TT * 4 + (tid - U)];
        if (tid == U + 4) { v0 = (_Float16)1.0f; v1 = (_Float16)1.0f; }
        hbb[0][tid] = v0;
        hbb[1][tid] = v1;
    }
    __syncthreads();

    float cstate = 0.0f;
    const float* __restrict__ xf = (const float*)xlds;
    const f32x4 zero4 = {0.f, 0.f, 0.f, 0.f};

    for (int t = 0; t < TT; ++t) {
        const int rb = t & 1, nb = rb ^ 1;

        // A-operand: 2 broadcast ds_read_b128 from h~(t)
        const uint4* hq = (const uint4*)&hbb[rb][0];
        uint4 a0u = hq[q];
        uint4 a1u = hq[4 + q];
        f16x8 A0 = __builtin_bit_cast(f16x8, a0u);
        f16x8 A1 = __builtin_bit_cast(f16x8, a1u);

        // x(t+1) for the h~ refill (q==0 lanes with unit in [50,54))
        float xnext = 0.0f;
        if (q == 0 && unit >= U && unit < U + 4)
            xnext = xf[((t + 1 < TT) ? (t + 1) : t) * 4 + (unit - U)];

        // 8 MFMA: 4 gates x 2 chained k-steps (independent across gates)
        f32x4 ai = __builtin_amdgcn_mfma_f32_16x16x32_f16(A0, wf[0][0], zero4, 0, 0, 0);
        f32x4 af = __builtin_amdgcn_mfma_f32_16x16x32_f16(A0, wf[1][0], zero4, 0, 0, 0);
        f32x4 ag = __builtin_amdgcn_mfma_f32_16x16x32_f16(A0, wf[2][0], zero4, 0, 0, 0);
        f32x4 ao = __builtin_amdgcn_mfma_f32_16x16x32_f16(A0, wf[3][0], zero4, 0, 0, 0);
        ai = __builtin_amdgcn_mfma_f32_16x16x32_f16(A1, wf[0][1], ai, 0, 0, 0);
        af = __builtin_amdgcn_mfma_f32_16x16x32_f16(A1, wf[1][1], af, 0, 0, 0);
        ag = __builtin_amdgcn_mfma_f32_16x16x32_f16(A1, wf[2][1], ag, 0, 0, 0);
        ao = __builtin_amdgcn_mfma_f32_16x16x32_f16(A1, wf[3][1], ao, 0, 0, 0);

        // D rows are redundant (A rows identical): reg 0 = full z per gate
        float gi = sigmoid_fast(ai[0]);
        float gf = sigmoid_fast(af[0]);
        float gg = tanh_fast(ag[0]);
        float go = sigmoid_fast(ao[0]);
        cstate = fmaf(gf, cstate, gi * gg);
        float hn = go * tanh_fast(cstate);

        // refill h~(t+1) in the OTHER buffer (no race with rb readers)
        if (q == 0) {
            if (unit < U)          hbb[nb][unit] = (_Float16)hn;
            else if (unit < U + 4) hbb[nb][unit] = (_Float16)xnext;
        }

        BAR();   // h~(t+1) complete & visible; buffers swap
    }

    // ---- 5 output heads (h(T) is in hbb[0]; TT even) ----
    if (tid < 5) {
        const float* wv = (tid == 0) ? w_dv : (tid == 1) ? w_dt :
                          (tid == 2) ? w_mj : (tid == 3) ? w_ma : w_mi;
        const float* bv = (tid == 0) ? b_dv : (tid == 1) ? b_dt :
                          (tid == 2) ? b_mj : (tid == 3) ? b_ma : b_mi;
        float s = bv[0];
        #pragma unroll
        for (int j = 0; j < U; ++j) s = fmaf((float)hbb[0][j], wv[j], s);
        float v;
        if (tid == 0)      v = param_act(s, 15.0f, 35.0f);
        else if (tid == 1) v = param_act(s, 0.5f, 3.0f);
        else if (tid == 2) v = fmaxf(s, 0.0f);
        else if (tid == 3) v = param_act(s, 0.5f, 3.0f);
        else               v = param_act(s, 0.5f, 4.0f);
        idm[tid] = v;
        out[BB * TT + b * 5 + tid] = v;
    }
    __syncthreads();

    // ---- IDM physics over T (threads 0..99, single pass) ----
    if (tid < TT) {
        const float desired_v    = idm[0];
        const float desired_tgap = idm[1];
        const float min_jamx     = idm[2];
        const float max_act      = idm[3];
        const float min_act      = idm[4];
        const float inv_tsab = 1.0f / (2.0f * sqrtf(max_act * min_act));
        const float inv_dv   = 1.0f / desired_v;
        float4 s4 = ((const float4*)(state + (size_t)b * TT * 4))[tid];
        float vel = s4.x, dv = s4.z, dx = s4.w;
        float dgap = fmaf(desired_tgap, vel, fmaf(vel * dv, inv_tsab, min_jamx));
        float r1 = vel * inv_dv;
        r1 = r1 * r1; r1 = r1 * r1;   // ^4
        float r2 = dgap / dx;
        r2 = r2 * r2;                 // ^2
        out[b * TT + tid] = max_act * (1.0f - (r1 + r2));
    }
}

extern "C" void kernel_launch(void* const* d_in, const int* in_sizes, int n_in,
                              void* d_out, int out_size, void* d_ws, size_t ws_size,
                              hipStream_t stream) {
    const float* x      = (const float*)d_in[0];
    const float* state  = (const float*)d_in[1];
    const float* kern   = (const float*)d_in[2];
    const float* rec    = (const float*)d_in[3];
    const float* bias   = (const float*)d_in[4];
    const float* w_dv   = (const float*)d_in[5];
    const float* b_dv   = (const float*)d_in[6];
    const float* w_dt   = (const float*)d_in[7];
    const float* b_dt   = (const float*)d_in[8];
    const float* w_mj   = (const float*)d_in[9];
    const float* b_mj   = (const float*)d_in[10];
    const float* w_ma   = (const float*)d_in[11];
    const float* b_ma   = (const float*)d_in[12];
    const float* w_mi   = (const float*)d_in[13];
    const float* b_mi   = (const float*)d_in[14];
    float* out = (float*)d_out;

    encoder_kernel<<<BB, 256, 0, stream>>>(
        x, state, kern, rec, bias,
        w_dv, b_dv, w_dt, b_dt, w_mj, b_mj, w_ma, b_ma, w_mi, b_mi,
        out);
}

// Round 22
// 43.207 us; speedup vs baseline: 1.2969x; 1.2969x over previous
//
#include <hip/hip_runtime.h>
#include <hip/hip_fp16.h>
#include <math.h>
#include <stdint.h>

#define U 50
#define TT 100
#define BB 256

typedef _Float16 half2v __attribute__((ext_vector_type(2)));

__device__ __forceinline__ float dot2_acc(uint32_t h2, uint32_t w2, float c) {
#if __has_builtin(__builtin_amdgcn_fdot2)
    return __builtin_amdgcn_fdot2(__builtin_bit_cast(half2v, h2),
                                  __builtin_bit_cast(half2v, w2), c, false);
#else
    half2v a = __builtin_bit_cast(half2v, h2);
    half2v b = __builtin_bit_cast(half2v, w2);
    return fmaf((float)a.x, (float)b.x, fmaf((float)a.y, (float)b.y, c));
#endif
}

__device__ __forceinline__ float sigmoid_fast(float x) {
    return 1.0f / (1.0f + __expf(-x));   // saturates cleanly, no NaN
}
__device__ __forceinline__ float tanh_fast(float x) {
    float e = __expf(2.0f * x);
    return 1.0f - 2.0f / (e + 1.0f);     // saturates cleanly, no NaN
}
__device__ __forceinline__ float param_act(float x, float mn, float mx) {
    float scale = 0.5f * (mx - mn);
    return tanh_fast(x) * scale + mn + scale;
}

// lgkm-only barrier: no vmcnt drain in the loop (round-14 lesson).
#define BAR() do {                                            \
    asm volatile("s_waitcnt lgkmcnt(0)" ::: "memory");        \
    __builtin_amdgcn_s_barrier();                             \
    asm volatile("" ::: "memory");                            \
} while (0)

// Round-14 champion structure + dep-chain cuts:
// FOUR waves per batch; wave w owns gate w (0=i,1=f,2=g,3=o) of unit l
// (25 packed f16 weight dwords/lane). One lgkm-only barrier per step; SoA
// conflict-free zex; redundant c/h on all waves; x pre-staged in LDS ->
// zero VMEM in the loop. NEW: 4 dot2 accumulator chains (dep depth 13->7)
// and an unroll-2 t-loop so the scheduler overlaps step t+1's x-part and
// weight restores with step t's c/h tail.
__global__ __launch_bounds__(256, 1) void encoder_kernel(
    const float* __restrict__ x,        // (B,T,4)
    const float* __restrict__ state,    // (B,T,4)
    const float* __restrict__ kernel,   // (4,200)
    const float* __restrict__ rec,      // (50,200)
    const float* __restrict__ bias,     // (200,)
    const float* __restrict__ w_dv, const float* __restrict__ b_dv,
    const float* __restrict__ w_dt, const float* __restrict__ b_dt,
    const float* __restrict__ w_mj, const float* __restrict__ b_mj,
    const float* __restrict__ w_ma, const float* __restrict__ b_ma,
    const float* __restrict__ w_mi, const float* __restrict__ b_mi,
    float* __restrict__ out)            // act_seq (B*T) then idm (B*5)
{
    const int b   = blockIdx.x;
    const int tid = threadIdx.x;
    const int w   = tid >> 6;           // gate owned by this wave (0..3)
    const int l   = tid & 63;
    const int cl  = (l < U) ? l : (U - 1);

    __shared__ __align__(16) float4 xlds[TT];        // staged x(b,:,:)  1600B
    __shared__ __align__(16) _Float16 h16[64];       // h state (f16)
    __shared__ float zex[2][4][64];                  // dbuf SoA nonlinearities
    __shared__ float idm[8];

    // ---- per-lane weights: gate w, column cl -- 25 packed dwords ----
    uint32_t wpk[25];
    #pragma unroll
    for (int j = 0; j < 25; ++j) {
        float r0 = rec[(2 * j) * 200 + w * U + cl];
        float r1 = rec[(2 * j + 1) * 200 + w * U + cl];
        half2v p; p.x = (_Float16)r0; p.y = (_Float16)r1;
        wpk[j] = __builtin_bit_cast(uint32_t, p);
    }
    #pragma unroll
    for (int j = 0; j < 25; ++j) asm volatile("" : "+v"(wpk[j]));

    float kc[4];
    #pragma unroll
    for (int f = 0; f < 4; ++f) kc[f] = kernel[f * 200 + w * U + cl];
    float bz = bias[w * U + cl];

    // ---- stage x into LDS, init h (full sync once) ----
    const float4* __restrict__ xg = (const float4*)(x + (size_t)b * TT * 4);
    if (tid < TT) xlds[tid] = xg[tid];
    if (tid < 64) h16[tid] = (_Float16)0.0f;
    __syncthreads();

    float cstate = 0.0f;
    uint32_t hvu[25];
    #pragma unroll
    for (int j = 0; j < 25; ++j) hvu[j] = 0u;   // h(0) = 0

    const uint4* __restrict__ hq = (const uint4*)h16;
    const uint32_t* __restrict__ hd = (const uint32_t*)h16;

    #pragma unroll 2
    for (int t = 0; t < TT; ++t) {
        const int buf = t & 1;
        float4 x4 = xlds[t];   // broadcast ds_read_b128

        // z for this wave's gate: x-part + 25 dot2 (4 chains, dep depth 7)
        float z = fmaf(x4.x, kc[0], fmaf(x4.y, kc[1],
                  fmaf(x4.z, kc[2], fmaf(x4.w, kc[3], bz))));
        float a0 = 0.f, a1 = 0.f, a2 = 0.f, a3 = 0.f;
        #pragma unroll
        for (int j = 0; j < 24; j += 4) {
            a0 = dot2_acc(hvu[j],     wpk[j],     a0);
            a1 = dot2_acc(hvu[j + 1], wpk[j + 1], a1);
            a2 = dot2_acc(hvu[j + 2], wpk[j + 2], a2);
            a3 = dot2_acc(hvu[j + 3], wpk[j + 3], a3);
        }
        a0 = dot2_acc(hvu[24], wpk[24], a0);
        z += (a0 + a1) + (a2 + a3);

        // own gate's nonlinearity (4 exps run in parallel across waves)
        float nl = (w == 2) ? tanh_fast(z) : sigmoid_fast(z);
        zex[buf][w][l] = nl;                 // stride-4B write: conflict-free

        BAR();                               // lgkm-only: zex(t) visible

        // reads first: 4x b32 issue back-to-back (latency overlapped)
        float gi = zex[buf][0][l];
        float gf = zex[buf][1][l];
        float gg = zex[buf][2][l];
        float go = zex[buf][3][l];
        cstate = fmaf(gf, cstate, gi * gg);
        float hn = go * tanh_fast(cstate);
        if (l < U) h16[l] = (_Float16)hn;    // 4x same-value write: benign

        // reload packed h(t+1); own-wave write->read is in-order (lgkmcnt)
        #pragma unroll
        for (int q = 0; q < 6; ++q) {
            uint4 v = hq[q];
            hvu[4 * q + 0] = v.x; hvu[4 * q + 1] = v.y;
            hvu[4 * q + 2] = v.z; hvu[4 * q + 3] = v.w;
        }
        hvu[24] = hd[24];
        // next iteration writes zex[(t+1)&1] -- the OTHER buffer, so the
        // single barrier suffices.
    }

    // ---- 5 output heads (threads 0..4; wave 0 wrote h16 itself) ----
    if (tid < 5) {
        const float* wv = (tid == 0) ? w_dv : (tid == 1) ? w_dt :
                          (tid == 2) ? w_mj : (tid == 3) ? w_ma : w_mi;
        const float* bv = (tid == 0) ? b_dv : (tid == 1) ? b_dt :
                          (tid == 2) ? b_mj : (tid == 3) ? b_ma : b_mi;
        float s = bv[0];
        #pragma unroll
        for (int j = 0; j < U; ++j) s = fmaf((float)h16[j], wv[j], s);
        float v;
        if (tid == 0)      v = param_act(s, 15.0f, 35.0f);
        else if (tid == 1) v = param_act(s, 0.5f, 3.0f);
        else if (tid == 2) v = fmaxf(s, 0.0f);
        else if (tid == 3) v = param_act(s, 0.5f, 3.0f);
        else               v = param_act(s, 0.5f, 4.0f);
        idm[tid] = v;
        out[BB * TT + b * 5 + tid] = v;
    }
    __syncthreads();

    // ---- IDM physics over T (256 threads) ----
    const float desired_v    = idm[0];
    const float desired_tgap = idm[1];
    const float min_jamx     = idm[2];
    const float max_act      = idm[3];
    const float min_act      = idm[4];
    const float inv_tsab = 1.0f / (2.0f * sqrtf(max_act * min_act));
    const float inv_dv   = 1.0f / desired_v;

    const float4* __restrict__ sb4 = (const float4*)(state + (size_t)b * TT * 4);
    for (int t = tid; t < TT; t += 256) {
        float4 s4 = sb4[t];
        float vel = s4.x;
        float dv  = s4.z;
        float dx  = s4.w;
        float dgap = fmaf(desired_tgap, vel, fmaf(vel * dv, inv_tsab, min_jamx));
        float r1 = vel * inv_dv;
        r1 = r1 * r1;
        r1 = r1 * r1;            // ^4
        float r2 = dgap / dx;
        r2 = r2 * r2;            // ^2
        out[b * TT + t] = max_act * (1.0f - (r1 + r2));
    }
}

extern "C" void kernel_launch(void* const* d_in, const int* in_sizes, int n_in,
                              void* d_out, int out_size, void* d_ws, size_t ws_size,
                              hipStream_t stream) {
    const float* x      = (const float*)d_in[0];
    const float* state  = (const float*)d_in[1];
    const float* kern   = (const float*)d_in[2];
    const float* rec    = (const float*)d_in[3];
    const float* bias   = (const float*)d_in[4];
    const float* w_dv   = (const float*)d_in[5];
    const float* b_dv   = (const float*)d_in[6];
    const float* w_dt   = (const float*)d_in[7];
    const float* b_dt   = (const float*)d_in[8];
    const float* w_mj   = (const float*)d_in[9];
    const float* b_mj   = (const float*)d_in[10];
    const float* w_ma   = (const float*)d_in[11];
    const float* b_ma   = (const float*)d_in[12];
    const float* w_mi   = (const float*)d_in[13];
    const float* b_mi   = (const float*)d_in[14];
    float* out = (float*)d_out;

    encoder_kernel<<<BB, 256, 0, stream>>>(
        x, state, kern, rec, bias,
        w_dv, b_dv, w_dt, b_dt, w_mj, b_mj, w_ma, b_ma, w_mi, b_mi,
        out);
}

// Round 23
// 41.309 us; speedup vs baseline: 1.3565x; 1.0459x over previous
//
#include <hip/hip_runtime.h>
#include <hip/hip_fp16.h>
#include <math.h>
#include <stdint.h>

#define U 50
#define TT 100
#define BB 256
#define LOG2E 1.44269504088896340736f

typedef _Float16 half2v __attribute__((ext_vector_type(2)));

__device__ __forceinline__ float dot2_acc(uint32_t h2, uint32_t w2, float c) {
#if __has_builtin(__builtin_amdgcn_fdot2)
    return __builtin_amdgcn_fdot2(__builtin_bit_cast(half2v, h2),
                                  __builtin_bit_cast(half2v, w2), c, false);
#else
    half2v a = __builtin_bit_cast(half2v, h2);
    half2v b = __builtin_bit_cast(half2v, w2);
    return fmaf((float)a.x, (float)b.x, fmaf((float)a.y, (float)b.y, c));
#endif
}

__device__ __forceinline__ float exp2_fast(float x) {
#if __has_builtin(__builtin_amdgcn_exp2f)
    return __builtin_amdgcn_exp2f(x);
#else
    return exp2f(x);
#endif
}

__device__ __forceinline__ float sigmoid_fast(float x) {
    return 1.0f / (1.0f + __expf(-x));   // saturates cleanly, no NaN
}
__device__ __forceinline__ float tanh_fast(float x) {
    float e = __expf(2.0f * x);
    return 1.0f - 2.0f / (e + 1.0f);     // saturates cleanly, no NaN
}
__device__ __forceinline__ float param_act(float x, float mn, float mx) {
    float scale = 0.5f * (mx - mn);
    return tanh_fast(x) * scale + mn + scale;
}

// lgkm-only barrier: no vmcnt drain in the loop (round-14 lesson).
#define BAR() do {                                            \
    asm volatile("s_waitcnt lgkmcnt(0)" ::: "memory");        \
    __builtin_amdgcn_s_barrier();                             \
    asm volatile("" ::: "memory");                            \
} while (0)

// Round-21 champion + final micros:
// FOUR waves per batch; wave w owns gate w (0=i,1=f,2=g,3=o) of unit l
// (25 packed f16 weight dwords/lane). One lgkm-only barrier per step; SoA
// conflict-free zex; redundant c/h on all waves; x pre-staged in LDS ->
// zero VMEM in the loop; 4 dot2 chains; unroll-4 t-loop.
// NEW: log2(e) (2*log2(e) for the tanh gate) is folded into the staged
// weights, so each gate nonlinearity uses raw v_exp_f32 without the
// 1.4427 multiply on the pre-barrier critical path.
__global__ __launch_bounds__(256, 1) void encoder_kernel(
    const float* __restrict__ x,        // (B,T,4)
    const float* __restrict__ state,    // (B,T,4)
    const float* __restrict__ kernel,   // (4,200)
    const float* __restrict__ rec,      // (50,200)
    const float* __restrict__ bias,     // (200,)
    const float* __restrict__ w_dv, const float* __restrict__ b_dv,
    const float* __restrict__ w_dt, const float* __restrict__ b_dt,
    const float* __restrict__ w_mj, const float* __restrict__ b_mj,
    const float* __restrict__ w_ma, const float* __restrict__ b_ma,
    const float* __restrict__ w_mi, const float* __restrict__ b_mi,
    float* __restrict__ out)            // act_seq (B*T) then idm (B*5)
{
    const int b   = blockIdx.x;
    const int tid = threadIdx.x;
    const int w   = tid >> 6;           // gate owned by this wave (0..3)
    const int l   = tid & 63;
    const int cl  = (l < U) ? l : (U - 1);

    __shared__ __align__(16) float4 xlds[TT];        // staged x(b,:,:)  1600B
    __shared__ __align__(16) _Float16 h16[64];       // h state (f16)
    __shared__ float zex[2][4][64];                  // dbuf SoA nonlinearities
    __shared__ float idm[8];

    // gate-specific prescale: sigmoid gates need exp(-z) = exp2(-log2e*z);
    // tanh gate needs exp(2z) = exp2(2*log2e*z).
    const float S = (w == 2) ? (2.0f * LOG2E) : LOG2E;

    // ---- per-lane weights: gate w, column cl -- 25 packed dwords (scaled) ----
    uint32_t wpk[25];
    #pragma unroll
    for (int j = 0; j < 25; ++j) {
        float r0 = rec[(2 * j) * 200 + w * U + cl] * S;
        float r1 = rec[(2 * j + 1) * 200 + w * U + cl] * S;
        half2v p; p.x = (_Float16)r0; p.y = (_Float16)r1;
        wpk[j] = __builtin_bit_cast(uint32_t, p);
    }
    #pragma unroll
    for (int j = 0; j < 25; ++j) asm volatile("" : "+v"(wpk[j]));

    float kc[4];
    #pragma unroll
    for (int f = 0; f < 4; ++f) kc[f] = kernel[f * 200 + w * U + cl] * S;
    float bz = bias[w * U + cl] * S;

    // ---- stage x into LDS, init h (full sync once) ----
    const float4* __restrict__ xg = (const float4*)(x + (size_t)b * TT * 4);
    if (tid < TT) xlds[tid] = xg[tid];
    if (tid < 64) h16[tid] = (_Float16)0.0f;
    __syncthreads();

    float cstate = 0.0f;
    uint32_t hvu[25];
    #pragma unroll
    for (int j = 0; j < 25; ++j) hvu[j] = 0u;   // h(0) = 0

    const uint4* __restrict__ hq = (const uint4*)h16;
    const uint32_t* __restrict__ hd = (const uint32_t*)h16;

    #pragma unroll 4
    for (int t = 0; t < TT; ++t) {
        const int buf = t & 1;
        float4 x4 = xlds[t];   // broadcast ds_read_b128

        // z' (prescaled) for this wave's gate: x-part + 25 dot2 (4 chains)
        float z = fmaf(x4.x, kc[0], fmaf(x4.y, kc[1],
                  fmaf(x4.z, kc[2], fmaf(x4.w, kc[3], bz))));
        float a0 = 0.f, a1 = 0.f, a2 = 0.f, a3 = 0.f;
        #pragma unroll
        for (int j = 0; j < 24; j += 4) {
            a0 = dot2_acc(hvu[j],     wpk[j],     a0);
            a1 = dot2_acc(hvu[j + 1], wpk[j + 1], a1);
            a2 = dot2_acc(hvu[j + 2], wpk[j + 2], a2);
            a3 = dot2_acc(hvu[j + 3], wpk[j + 3], a3);
        }
        a0 = dot2_acc(hvu[24], wpk[24], a0);
        z += (a0 + a1) + (a2 + a3);

        // own gate's nonlinearity via raw exp2 (prescale folded into weights)
        float nl;
        if (w == 2) nl = 1.0f - 2.0f / (exp2_fast(z) + 1.0f);   // tanh(z_true)
        else        nl = 1.0f / (1.0f + exp2_fast(-z));         // sigmoid(z_true)
        zex[buf][w][l] = nl;                 // stride-4B write: conflict-free

        BAR();                               // lgkm-only: zex(t) visible

        // reads first: 4x b32 issue back-to-back (latency overlapped)
        float gi = zex[buf][0][l];
        float gf = zex[buf][1][l];
        float gg = zex[buf][2][l];
        float go = zex[buf][3][l];
        cstate = fmaf(gf, cstate, gi * gg);
        float hn = go * tanh_fast(cstate);
        if (l < U) h16[l] = (_Float16)hn;    // 4x same-value write: benign

        // reload packed h(t+1); own-wave write->read is in-order (lgkmcnt);
        // completion is drained inside the next BAR's lgkmcnt(0).
        #pragma unroll
        for (int q = 0; q < 6; ++q) {
            uint4 v = hq[q];
            hvu[4 * q + 0] = v.x; hvu[4 * q + 1] = v.y;
            hvu[4 * q + 2] = v.z; hvu[4 * q + 3] = v.w;
        }
        hvu[24] = hd[24];
        // next iteration writes zex[(t+1)&1] -- the OTHER buffer, so the
        // single barrier suffices.
    }

    // ---- 5 output heads (threads 0..4; wave 0 wrote h16 itself) ----
    if (tid < 5) {
        const float* wv = (tid == 0) ? w_dv : (tid == 1) ? w_dt :
                          (tid == 2) ? w_mj : (tid == 3) ? w_ma : w_mi;
        const float* bv = (tid == 0) ? b_dv : (tid == 1) ? b_dt :
                          (tid == 2) ? b_mj : (tid == 3) ? b_ma : b_mi;
        float s = bv[0];
        #pragma unroll
        for (int j = 0; j < U; ++j) s = fmaf((float)h16[j], wv[j], s);
        float v;
        if (tid == 0)      v = param_act(s, 15.0f, 35.0f);
        else if (tid == 1) v = param_act(s, 0.5f, 3.0f);
        else if (tid == 2) v = fmaxf(s, 0.0f);
        else if (tid == 3) v = param_act(s, 0.5f, 3.0f);
        else               v = param_act(s, 0.5f, 4.0f);
        idm[tid] = v;
        out[BB * TT + b * 5 + tid] = v;
    }
    __syncthreads();

    // ---- IDM physics over T (256 threads) ----
    const float desired_v    = idm[0];
    const float desired_tgap = idm[1];
    const float min_jamx     = idm[2];
    const float max_act      = idm[3];
    const float min_act      = idm[4];
    const float inv_tsab = 1.0f / (2.0f * sqrtf(max_act * min_act));
    const float inv_dv   = 1.0f / desired_v;

    const float4* __restrict__ sb4 = (const float4*)(state + (size_t)b * TT * 4);
    for (int t = tid; t < TT; t += 256) {
        float4 s4 = sb4[t];
        float vel = s4.x;
        float dv  = s4.z;
        float dx  = s4.w;
        float dgap = fmaf(desired_tgap, vel, fmaf(vel * dv, inv_tsab, min_jamx));
        float r1 = vel * inv_dv;
        r1 = r1 * r1;
        r1 = r1 * r1;            // ^4
        float r2 = dgap / dx;
        r2 = r2 * r2;            // ^2
        out[b * TT + t] = max_act * (1.0f - (r1 + r2));
    }
}

extern "C" void kernel_launch(void* const* d_in, const int* in_sizes, int n_in,
                              void* d_out, int out_size, void* d_ws, size_t ws_size,
                              hipStream_t stream) {
    const float* x      = (const float*)d_in[0];
    const float* state  = (const float*)d_in[1];
    const float* kern   = (const float*)d_in[2];
    const float* rec    = (const float*)d_in[3];
    const float* bias   = (const float*)d_in[4];
    const float* w_dv   = (const float*)d_in[5];
    const float* b_dv   = (const float*)d_in[6];
    const float* w_dt   = (const float*)d_in[7];
    const float* b_dt   = (const float*)d_in[8];
    const float* w_mj   = (const float*)d_in[9];
    const float* b_mj   = (const float*)d_in[10];
    const float* w_ma   = (const float*)d_in[11];
    const float* b_ma   = (const float*)d_in[12];
    const float* w_mi   = (const float*)d_in[13];
    const float* b_mi   = (const float*)d_in[14];
    float* out = (float*)d_out;

    encoder_kernel<<<BB, 256, 0, stream>>>(
        x, state, kern, rec, bias,
        w_dv, b_dv, w_dt, b_dt, w_mj, b_mj, w_ma, b_ma, w_mi, b_mi,
        out);
}

// Round 24
// 37.502 us; speedup vs baseline: 1.4942x; 1.1015x over previous
//
#include <hip/hip_runtime.h>
#include <hip/hip_fp16.h>
#include <math.h>
#include <stdint.h>

#define U 50
#define TT 100
#define BB 256
#define LOG2E 1.44269504088896340736f

typedef _Float16 half2v __attribute__((ext_vector_type(2)));

__device__ __forceinline__ float dot2_acc(uint32_t h2, uint32_t w2, float c) {
#if __has_builtin(__builtin_amdgcn_fdot2)
    return __builtin_amdgcn_fdot2(__builtin_bit_cast(half2v, h2),
                                  __builtin_bit_cast(half2v, w2), c, false);
#else
    half2v a = __builtin_bit_cast(half2v, h2);
    half2v b = __builtin_bit_cast(half2v, w2);
    return fmaf((float)a.x, (float)b.x, fmaf((float)a.y, (float)b.y, c));
#endif
}

__device__ __forceinline__ float exp2_fast(float x) {
#if __has_builtin(__builtin_amdgcn_exp2f)
    return __builtin_amdgcn_exp2f(x);
#else
    return exp2f(x);
#endif
}

// Single v_rcp_f32 (1 ulp) instead of the IEEE div expansion (~9 serial ops)
// hipcc emits for 1.0f/x without -ffast-math. Two of these sat on the
// per-step serial path in every prior round.
__device__ __forceinline__ float rcp_fast(float x) {
#if __has_builtin(__builtin_amdgcn_rcpf)
    return __builtin_amdgcn_rcpf(x);
#else
    return 1.0f / x;
#endif
}

__device__ __forceinline__ float tanh_fast(float x) {
    float e = __expf(2.0f * x);
    return fmaf(-2.0f, rcp_fast(e + 1.0f), 1.0f);   // saturates cleanly
}
__device__ __forceinline__ float param_act(float x, float mn, float mx) {
    float scale = 0.5f * (mx - mn);
    return tanh_fast(x) * scale + mn + scale;
}

// lgkm-only barrier: no vmcnt drain in the loop (round-14 lesson).
#define BAR() do {                                            \
    asm volatile("s_waitcnt lgkmcnt(0)" ::: "memory");        \
    __builtin_amdgcn_s_barrier();                             \
    asm volatile("" ::: "memory");                            \
} while (0)

// Round-22 champion + serial-path cuts:
// FOUR waves per batch; wave w owns gate w (0=i,1=f,2=g,3=o) of unit l
// (25 packed f16 weight dwords/lane, log2e-prescaled). One lgkm-only
// barrier per step; SoA conflict-free zex; redundant c/h on all waves;
// x pre-staged in LDS -> zero VMEM in the loop; 4 dot2 chains; unroll-4.
// NEW: (1) v_rcp_f32 replaces both per-step IEEE divisions; (2) the i-gate
// nonlinearity is stored pre-scaled by 2*log2e so cstate carries the tanh
// prescale -> post-barrier tanh needs no multiply before exp2;
// (3) hn = fmaf(-2go, r, go) with go+go computed off the serial path.
__global__ __launch_bounds__(256, 1) void encoder_kernel(
    const float* __restrict__ x,        // (B,T,4)
    const float* __restrict__ state,    // (B,T,4)
    const float* __restrict__ kernel,   // (4,200)
    const float* __restrict__ rec,      // (50,200)
    const float* __restrict__ bias,     // (200,)
    const float* __restrict__ w_dv, const float* __restrict__ b_dv,
    const float* __restrict__ w_dt, const float* __restrict__ b_dt,
    const float* __restrict__ w_mj, const float* __restrict__ b_mj,
    const float* __restrict__ w_ma, const float* __restrict__ b_ma,
    const float* __restrict__ w_mi, const float* __restrict__ b_mi,
    float* __restrict__ out)            // act_seq (B*T) then idm (B*5)
{
    const int b   = blockIdx.x;
    const int tid = threadIdx.x;
    const int w   = tid >> 6;           // gate owned by this wave (0..3)
    const int l   = tid & 63;
    const int cl  = (l < U) ? l : (U - 1);

    __shared__ __align__(16) float4 xlds[TT];        // staged x(b,:,:)  1600B
    __shared__ __align__(16) _Float16 h16[64];       // h state (f16)
    __shared__ float zex[2][4][64];                  // dbuf SoA nonlinearities
    __shared__ float idm[8];

    // gate-specific prescale: sigmoid gates need exp(-z) = exp2(-log2e*z);
    // tanh gate needs exp(2z) = exp2(2*log2e*z).
    const float S = (w == 2) ? (2.0f * LOG2E) : LOG2E;

    // ---- per-lane weights: gate w, column cl -- 25 packed dwords (scaled) ----
    uint32_t wpk[25];
    #pragma unroll
    for (int j = 0; j < 25; ++j) {
        float r0 = rec[(2 * j) * 200 + w * U + cl] * S;
        float r1 = rec[(2 * j + 1) * 200 + w * U + cl] * S;
        half2v p; p.x = (_Float16)r0; p.y = (_Float16)r1;
        wpk[j] = __builtin_bit_cast(uint32_t, p);
    }
    #pragma unroll
    for (int j = 0; j < 25; ++j) asm volatile("" : "+v"(wpk[j]));

    float kc[4];
    #pragma unroll
    for (int f = 0; f < 4; ++f) kc[f] = kernel[f * 200 + w * U + cl] * S;
    float bz = bias[w * U + cl] * S;

    // ---- stage x into LDS, init h (full sync once) ----
    const float4* __restrict__ xg = (const float4*)(x + (size_t)b * TT * 4);
    if (tid < TT) xlds[tid] = xg[tid];
    if (tid < 64) h16[tid] = (_Float16)0.0f;
    __syncthreads();

    float cstate = 0.0f;                // carries 2*log2e * c (prescaled)
    uint32_t hvu[25];
    #pragma unroll
    for (int j = 0; j < 25; ++j) hvu[j] = 0u;   // h(0) = 0

    const uint4* __restrict__ hq = (const uint4*)h16;
    const uint32_t* __restrict__ hd = (const uint32_t*)h16;

    #pragma unroll 4
    for (int t = 0; t < TT; ++t) {
        const int buf = t & 1;
        float4 x4 = xlds[t];   // broadcast ds_read_b128

        // z' (prescaled) for this wave's gate: x-part + 25 dot2 (4 chains)
        float z = fmaf(x4.x, kc[0], fmaf(x4.y, kc[1],
                  fmaf(x4.z, kc[2], fmaf(x4.w, kc[3], bz))));
        float a0 = 0.f, a1 = 0.f, a2 = 0.f, a3 = 0.f;
        #pragma unroll
        for (int j = 0; j < 24; j += 4) {
            a0 = dot2_acc(hvu[j],     wpk[j],     a0);
            a1 = dot2_acc(hvu[j + 1], wpk[j + 1], a1);
            a2 = dot2_acc(hvu[j + 2], wpk[j + 2], a2);
            a3 = dot2_acc(hvu[j + 3], wpk[j + 3], a3);
        }
        a0 = dot2_acc(hvu[24], wpk[24], a0);
        z += (a0 + a1) + (a2 + a3);

        // own gate's nonlinearity via raw exp2 + v_rcp (no IEEE div).
        // Wave 0 (i-gate) stores 2*log2e * sigmoid so cstate is prescaled
        // for the post-barrier tanh.
        float nl;
        if (w == 2)      nl = fmaf(-2.0f, rcp_fast(exp2_fast(z) + 1.0f), 1.0f);
        else if (w == 0) nl = (2.0f * LOG2E) * rcp_fast(1.0f + exp2_fast(-z));
        else             nl = rcp_fast(1.0f + exp2_fast(-z));
        zex[buf][w][l] = nl;                 // stride-4B write: conflict-free

        BAR();                               // lgkm-only: zex(t) visible

        // reads first: 4x b32 issue back-to-back (latency overlapped)
        float gi = zex[buf][0][l];           // pre-scaled by 2*log2e
        float gf = zex[buf][1][l];
        float gg = zex[buf][2][l];
        float go = zex[buf][3][l];
        cstate = fmaf(gf, cstate, gi * gg);  // = 2*log2e * c(t)
        float e  = exp2_fast(cstate);        // exp(2c)
        float r  = rcp_fast(e + 1.0f);
        float go2 = go + go;                 // off the serial chain
        float hn = fmaf(-go2, r, go);        // go * tanh(c)
        if (l < U) h16[l] = (_Float16)hn;    // 4x same-value write: benign

        // reload packed h(t+1); own-wave write->read is in-order (lgkmcnt);
        // completion is drained inside the next BAR's lgkmcnt(0).
        #pragma unroll
        for (int q = 0; q < 6; ++q) {
            uint4 v = hq[q];
            hvu[4 * q + 0] = v.x; hvu[4 * q + 1] = v.y;
            hvu[4 * q + 2] = v.z; hvu[4 * q + 3] = v.w;
        }
        hvu[24] = hd[24];
        // next iteration writes zex[(t+1)&1] -- the OTHER buffer, so the
        // single barrier suffices.
    }

    // ---- 5 output heads (threads 0..4; wave 0 wrote h16 itself) ----
    if (tid < 5) {
        const float* wv = (tid == 0) ? w_dv : (tid == 1) ? w_dt :
                          (tid == 2) ? w_mj : (tid == 3) ? w_ma : w_mi;
        const float* bv = (tid == 0) ? b_dv : (tid == 1) ? b_dt :
                          (tid == 2) ? b_mj : (tid == 3) ? b_ma : b_mi;
        float s = bv[0];
        #pragma unroll
        for (int j = 0; j < U; ++j) s = fmaf((float)h16[j], wv[j], s);
        float v;
        if (tid == 0)      v = param_act(s, 15.0f, 35.0f);
        else if (tid == 1) v = param_act(s, 0.5f, 3.0f);
        else if (tid == 2) v = fmaxf(s, 0.0f);
        else if (tid == 3) v = param_act(s, 0.5f, 3.0f);
        else               v = param_act(s, 0.5f, 4.0f);
        idm[tid] = v;
        out[BB * TT + b * 5 + tid] = v;
    }
    __syncthreads();

    // ---- IDM physics over T (256 threads) ----
    const float desired_v    = idm[0];
    const float desired_tgap = idm[1];
    const float min_jamx     = idm[2];
    const float max_act      = idm[3];
    const float min_act      = idm[4];
    const float inv_tsab = 1.0f / (2.0f * sqrtf(max_act * min_act));
    const float inv_dv   = 1.0f / desired_v;

    const float4* __restrict__ sb4 = (const float4*)(state + (size_t)b * TT * 4);
    for (int t = tid; t < TT; t += 256) {
        float4 s4 = sb4[t];
        float vel = s4.x;
        float dv  = s4.z;
        float dx  = s4.w;
        float dgap = fmaf(desired_tgap, vel, fmaf(vel * dv, inv_tsab, min_jamx));
        float r1 = vel * inv_dv;
        r1 = r1 * r1;
        r1 = r1 * r1;            // ^4
        float r2 = dgap / dx;
        r2 = r2 * r2;            // ^2
        out[b * TT + t] = max_act * (1.0f - (r1 + r2));
    }
}

extern "C" void kernel_launch(void* const* d_in, const int* in_sizes, int n_in,
                              void* d_out, int out_size, void* d_ws, size_t ws_size,
                              hipStream_t stream) {
    const float* x      = (const float*)d_in[0];
    const float* state  = (const float*)d_in[1];
    const float* kern   = (const float*)d_in[2];
    const float* rec    = (const float*)d_in[3];
    const float* bias   = (const float*)d_in[4];
    const float* w_dv   = (const float*)d_in[5];
    const float* b_dv   = (const float*)d_in[6];
    const float* w_dt   = (const float*)d_in[7];
    const float* b_dt   = (const float*)d_in[8];
    const float* w_mj   = (const float*)d_in[9];
    const float* b_mj   = (const float*)d_in[10];
    const float* w_ma   = (const float*)d_in[11];
    const float* b_ma   = (const float*)d_in[12];
    const float* w_mi   = (const float*)d_in[13];
    const float* b_mi   = (const float*)d_in[14];
    float* out = (float*)d_out;

    encoder_kernel<<<BB, 256, 0, stream>>>(
        x, state, kern, rec, bias,
        w_dv, b_dv, w_dt, b_dt, w_mj, b_mj, w_ma, b_ma, w_mi, b_mi,
        out);
}